// Round 10
// baseline (50.280 us; speedup 1.0000x reference)
//
#include <hip/hip_runtime.h>

typedef float f4 __attribute__((ext_vector_type(4)));
typedef int   i4 __attribute__((ext_vector_type(4)));

#define HWD   (512 * 512)      // pixels per image
#define P4    (HWD / 4)        // float4 per class plane
#define NCLS  8
#define NBATCH 16
#define MAIN_GX 64             // blocks per image
#define MAIN_BLK 512
#define NBLK  (NBATCH * MAIN_GX)      // 1024 blocks

// 64-lane wave reduction
#define WRED(x) { x += __shfl_down(x, 32); x += __shfl_down(x, 16); x += __shfl_down(x, 8); \
                  x += __shfl_down(x, 4);  x += __shfl_down(x, 2);  x += __shfl_down(x, 1); }

// R9 kernel with ONE change: each thread handles 2 ADJACENT float4 positions
// (j = 2*gtid, 2*gtid+1) instead of two grid-strided ones 512KB apart.
// Wave x plane footprint: 2KB contiguous (was 2 x 1KB, 1MB apart). Single-
// variable A/B for DRAM-locality sensitivity of the 5.1 TB/s plateau.
__global__ void __launch_bounds__(MAIN_BLK) wce_main(const float* __restrict__ pred,
                                                     const int* __restrict__ target,
                                                     float* __restrict__ pS,   // [c][NBLK]
                                                     int* __restrict__ pC) {   // [c][NBLK]
    const int n = blockIdx.y, bx = blockIdx.x;
    const f4* p4  = (const f4*)(pred + (size_t)n * NCLS * HWD);
    const i4* tg4 = (const i4*)(target + (size_t)n * HWD);

    float s0=0,s1=0,s2=0,s3=0,s4=0,s5=0,s6=0,s7=0;
    int   k0=0,k1=0,k2=0,k3=0,k4=0,k5=0,k6=0,k7=0;

    int j = (bx * MAIN_BLK + (int)threadIdx.x) * 2;
    for (int it = 0; it < 2; ++it, ++j) {   // two ADJACENT positions
        i4 t4 = tg4[j];
        f4 l0 = __builtin_nontemporal_load(p4 + 0 * P4 + j);
        f4 l1 = __builtin_nontemporal_load(p4 + 1 * P4 + j);
        f4 l2 = __builtin_nontemporal_load(p4 + 2 * P4 + j);
        f4 l3 = __builtin_nontemporal_load(p4 + 3 * P4 + j);
        f4 l4 = __builtin_nontemporal_load(p4 + 4 * P4 + j);
        f4 l5 = __builtin_nontemporal_load(p4 + 5 * P4 + j);
        f4 l6 = __builtin_nontemporal_load(p4 + 6 * P4 + j);
        f4 l7 = __builtin_nontemporal_load(p4 + 7 * P4 + j);
#define PIX(F, T) { \
        int t = min(max((T), 0), 7); \
        float a0 = l0.F, a1 = l1.F, a2 = l2.F, a3 = l3.F; \
        float a4 = l4.F, a5 = l5.F, a6 = l6.F, a7 = l7.F; \
        float s = __expf(a0) + __expf(a1) + __expf(a2) + __expf(a3) + \
                  __expf(a4) + __expf(a5) + __expf(a6) + __expf(a7); \
        float at = t == 0 ? a0 : t == 1 ? a1 : t == 2 ? a2 : t == 3 ? a3 : \
                   t == 4 ? a4 : t == 5 ? a5 : t == 6 ? a6 : a7; \
        float lp = at - __logf(s); \
        s0 += (t == 0) ? lp : 0.0f; s1 += (t == 1) ? lp : 0.0f; \
        s2 += (t == 2) ? lp : 0.0f; s3 += (t == 3) ? lp : 0.0f; \
        s4 += (t == 4) ? lp : 0.0f; s5 += (t == 5) ? lp : 0.0f; \
        s6 += (t == 6) ? lp : 0.0f; s7 += (t == 7) ? lp : 0.0f; \
        k0 += (t == 0); k1 += (t == 1); k2 += (t == 2); k3 += (t == 3); \
        k4 += (t == 4); k5 += (t == 5); k6 += (t == 6); k7 += (t == 7); }
        PIX(x, t4.x) PIX(y, t4.y) PIX(z, t4.z) PIX(w, t4.w)
#undef PIX
    }

    WRED(s0) WRED(s1) WRED(s2) WRED(s3) WRED(s4) WRED(s5) WRED(s6) WRED(s7)
    WRED(k0) WRED(k1) WRED(k2) WRED(k3) WRED(k4) WRED(k5) WRED(k6) WRED(k7)

    __shared__ float ls[MAIN_BLK / 64][8];
    __shared__ int   li[MAIN_BLK / 64][8];
    const int wave = threadIdx.x >> 6;
    if ((threadIdx.x & 63) == 0) {
        ls[wave][0] = s0; ls[wave][1] = s1; ls[wave][2] = s2; ls[wave][3] = s3;
        ls[wave][4] = s4; ls[wave][5] = s5; ls[wave][6] = s6; ls[wave][7] = s7;
        li[wave][0] = k0; li[wave][1] = k1; li[wave][2] = k2; li[wave][3] = k3;
        li[wave][4] = k4; li[wave][5] = k5; li[wave][6] = k6; li[wave][7] = k7;
    }
    __syncthreads();
    if (threadIdx.x < 8) {
        int c = threadIdx.x;
        float v = 0.0f;
#pragma unroll
        for (int w = 0; w < MAIN_BLK / 64; ++w) v += ls[w][c];
        pS[c * NBLK + n * MAIN_GX + bx] = v;
    } else if (threadIdx.x < 16) {
        int c = threadIdx.x - 8;
        int v = 0;
#pragma unroll
        for (int w = 0; w < MAIN_BLK / 64; ++w) v += li[w][c];
        pC[c * NBLK + n * MAIN_GX + bx] = v;
    }
}

// ---------------- Kernel 2: finalize (reads 64 KB of partials) ----------------
__global__ void __launch_bounds__(1024) wce_final(const float* __restrict__ pS,
                                                  const int* __restrict__ pC,
                                                  float* __restrict__ out) {
    const int wave = threadIdx.x >> 6;  // 16 waves
    const int lane = threadIdx.x & 63;
    __shared__ float gc[16];
    __shared__ float wtab[8];
    __shared__ float r[16];

    // Phase A: global class counts. wave w -> class c = w>>1, half h = w&1 (512 ints each).
    {
        const int c = wave >> 1, h = wave & 1;
        const int* base = pC + c * NBLK + h * (NBLK / 2);
        int acc = 0;
#pragma unroll
        for (int k = 0; k < NBLK / 2 / 64; ++k) acc += base[lane + k * 64];
        WRED(acc)
        if (lane == 0) gc[wave] = (float)acc;
    }
    __syncthreads();
    if (threadIdx.x < 8)
        wtab[threadIdx.x] = 1.0f / (gc[2 * threadIdx.x] + gc[2 * threadIdx.x + 1] + 1e-6f);
    __syncthreads();

    // Phase B: wave w = image n; exactly MAIN_GX=64 partials per (c, img) -> one per lane.
    {
        const int n = wave;
        float num = 0.0f, den = 0.0f;
#pragma unroll
        for (int c = 0; c < 8; ++c) {
            float sv = pS[c * NBLK + n * MAIN_GX + lane];
            float cv = (float)pC[c * NBLK + n * MAIN_GX + lane];
            float w = wtab[c];
            num += w * sv;
            den += w * cv;
        }
        WRED(num) WRED(den)
        if (lane == 0) r[n] = num / den;
    }
    __syncthreads();
    if (threadIdx.x == 0) {
        float s = 0.0f;
#pragma unroll
        for (int k = 0; k < 16; ++k) s += r[k];
        out[0] = -s / 16.0f;
    }
}

extern "C" void kernel_launch(void* const* d_in, const int* in_sizes, int n_in,
                              void* d_out, int out_size, void* d_ws, size_t ws_size,
                              hipStream_t stream) {
    const float* pred = (const float*)d_in[0];
    const int* target = (const int*)d_in[1];

    // ws layout: pS [8][1024] floats | pC [8][1024] ints (every slot written by wce_main)
    float* pS = (float*)d_ws;
    int* pC = (int*)(pS + NCLS * NBLK);

    hipLaunchKernelGGL(wce_main, dim3(MAIN_GX, NBATCH), dim3(MAIN_BLK), 0, stream,
                       pred, target, pS, pC);
    hipLaunchKernelGGL(wce_final, dim3(1), dim3(1024), 0, stream, pS, pC, (float*)d_out);
}

// Round 11
// 33.748 us; speedup vs baseline: 1.4899x; 1.4899x over previous
//
#include <hip/hip_runtime.h>

typedef float f4 __attribute__((ext_vector_type(4)));
typedef int   i4 __attribute__((ext_vector_type(4)));

#define HWD   (512 * 512)      // pixels per image
#define P4    (HWD / 4)        // float4 per class plane
#define NCLS  8
#define NBATCH 16
#define MAIN_GX 64             // blocks per image
#define MAIN_BLK 512
#define NBLK  (NBATCH * MAIN_GX)      // 1024 blocks
#define STRIDE (MAIN_GX * MAIN_BLK)   // 32768 threads per image

// 64-lane wave reduction
#define WRED(x) { x += __shfl_down(x, 32); x += __shfl_down(x, 16); x += __shfl_down(x, 8); \
                  x += __shfl_down(x, 4);  x += __shfl_down(x, 2);  x += __shfl_down(x, 1); }

// R9 kernel (best: 33.7us) -- reverted from R10's stride-2 experiment, which
// broke per-instruction coalescing (50.3us). Lane-unit-stride grid-strided
// loop, nt pred loads, no-max LSE, 512-thread blocks, 64KB partials.
__global__ void __launch_bounds__(MAIN_BLK) wce_main(const float* __restrict__ pred,
                                                     const int* __restrict__ target,
                                                     float* __restrict__ pS,   // [c][NBLK]
                                                     int* __restrict__ pC) {   // [c][NBLK]
    const int n = blockIdx.y, bx = blockIdx.x;
    const f4* p4  = (const f4*)(pred + (size_t)n * NCLS * HWD);
    const i4* tg4 = (const i4*)(target + (size_t)n * HWD);

    float s0=0,s1=0,s2=0,s3=0,s4=0,s5=0,s6=0,s7=0;
    int   k0=0,k1=0,k2=0,k3=0,k4=0,k5=0,k6=0,k7=0;

    int tid = bx * MAIN_BLK + (int)threadIdx.x;
    for (int i = tid; i < HWD / 4; i += STRIDE) {   // exactly 2 iterations
        i4 t4 = tg4[i];
        f4 l0 = __builtin_nontemporal_load(p4 + 0 * P4 + i);
        f4 l1 = __builtin_nontemporal_load(p4 + 1 * P4 + i);
        f4 l2 = __builtin_nontemporal_load(p4 + 2 * P4 + i);
        f4 l3 = __builtin_nontemporal_load(p4 + 3 * P4 + i);
        f4 l4 = __builtin_nontemporal_load(p4 + 4 * P4 + i);
        f4 l5 = __builtin_nontemporal_load(p4 + 5 * P4 + i);
        f4 l6 = __builtin_nontemporal_load(p4 + 6 * P4 + i);
        f4 l7 = __builtin_nontemporal_load(p4 + 7 * P4 + i);
#define PIX(F, T) { \
        int t = min(max((T), 0), 7); \
        float a0 = l0.F, a1 = l1.F, a2 = l2.F, a3 = l3.F; \
        float a4 = l4.F, a5 = l5.F, a6 = l6.F, a7 = l7.F; \
        float s = __expf(a0) + __expf(a1) + __expf(a2) + __expf(a3) + \
                  __expf(a4) + __expf(a5) + __expf(a6) + __expf(a7); \
        float at = t == 0 ? a0 : t == 1 ? a1 : t == 2 ? a2 : t == 3 ? a3 : \
                   t == 4 ? a4 : t == 5 ? a5 : t == 6 ? a6 : a7; \
        float lp = at - __logf(s); \
        s0 += (t == 0) ? lp : 0.0f; s1 += (t == 1) ? lp : 0.0f; \
        s2 += (t == 2) ? lp : 0.0f; s3 += (t == 3) ? lp : 0.0f; \
        s4 += (t == 4) ? lp : 0.0f; s5 += (t == 5) ? lp : 0.0f; \
        s6 += (t == 6) ? lp : 0.0f; s7 += (t == 7) ? lp : 0.0f; \
        k0 += (t == 0); k1 += (t == 1); k2 += (t == 2); k3 += (t == 3); \
        k4 += (t == 4); k5 += (t == 5); k6 += (t == 6); k7 += (t == 7); }
        PIX(x, t4.x) PIX(y, t4.y) PIX(z, t4.z) PIX(w, t4.w)
#undef PIX
    }

    WRED(s0) WRED(s1) WRED(s2) WRED(s3) WRED(s4) WRED(s5) WRED(s6) WRED(s7)
    WRED(k0) WRED(k1) WRED(k2) WRED(k3) WRED(k4) WRED(k5) WRED(k6) WRED(k7)

    __shared__ float ls[MAIN_BLK / 64][8];
    __shared__ int   li[MAIN_BLK / 64][8];
    const int wave = threadIdx.x >> 6;
    if ((threadIdx.x & 63) == 0) {
        ls[wave][0] = s0; ls[wave][1] = s1; ls[wave][2] = s2; ls[wave][3] = s3;
        ls[wave][4] = s4; ls[wave][5] = s5; ls[wave][6] = s6; ls[wave][7] = s7;
        li[wave][0] = k0; li[wave][1] = k1; li[wave][2] = k2; li[wave][3] = k3;
        li[wave][4] = k4; li[wave][5] = k5; li[wave][6] = k6; li[wave][7] = k7;
    }
    __syncthreads();
    if (threadIdx.x < 8) {
        int c = threadIdx.x;
        float v = 0.0f;
#pragma unroll
        for (int w = 0; w < MAIN_BLK / 64; ++w) v += ls[w][c];
        pS[c * NBLK + n * MAIN_GX + bx] = v;
    } else if (threadIdx.x < 16) {
        int c = threadIdx.x - 8;
        int v = 0;
#pragma unroll
        for (int w = 0; w < MAIN_BLK / 64; ++w) v += li[w][c];
        pC[c * NBLK + n * MAIN_GX + bx] = v;
    }
}

// ---------------- Kernel 2: finalize (reads 64 KB of partials) ----------------
__global__ void __launch_bounds__(1024) wce_final(const float* __restrict__ pS,
                                                  const int* __restrict__ pC,
                                                  float* __restrict__ out) {
    const int wave = threadIdx.x >> 6;  // 16 waves
    const int lane = threadIdx.x & 63;
    __shared__ float gc[16];
    __shared__ float wtab[8];
    __shared__ float r[16];

    // Phase A: global class counts. wave w -> class c = w>>1, half h = w&1 (512 ints each).
    {
        const int c = wave >> 1, h = wave & 1;
        const int* base = pC + c * NBLK + h * (NBLK / 2);
        int acc = 0;
#pragma unroll
        for (int k = 0; k < NBLK / 2 / 64; ++k) acc += base[lane + k * 64];
        WRED(acc)
        if (lane == 0) gc[wave] = (float)acc;
    }
    __syncthreads();
    if (threadIdx.x < 8)
        wtab[threadIdx.x] = 1.0f / (gc[2 * threadIdx.x] + gc[2 * threadIdx.x + 1] + 1e-6f);
    __syncthreads();

    // Phase B: wave w = image n; exactly MAIN_GX=64 partials per (c, img) -> one per lane.
    {
        const int n = wave;
        float num = 0.0f, den = 0.0f;
#pragma unroll
        for (int c = 0; c < 8; ++c) {
            float sv = pS[c * NBLK + n * MAIN_GX + lane];
            float cv = (float)pC[c * NBLK + n * MAIN_GX + lane];
            float w = wtab[c];
            num += w * sv;
            den += w * cv;
        }
        WRED(num) WRED(den)
        if (lane == 0) r[n] = num / den;
    }
    __syncthreads();
    if (threadIdx.x == 0) {
        float s = 0.0f;
#pragma unroll
        for (int k = 0; k < 16; ++k) s += r[k];
        out[0] = -s / 16.0f;
    }
}

extern "C" void kernel_launch(void* const* d_in, const int* in_sizes, int n_in,
                              void* d_out, int out_size, void* d_ws, size_t ws_size,
                              hipStream_t stream) {
    const float* pred = (const float*)d_in[0];
    const int* target = (const int*)d_in[1];

    // ws layout: pS [8][1024] floats | pC [8][1024] ints (every slot written by wce_main)
    float* pS = (float*)d_ws;
    int* pC = (int*)(pS + NCLS * NBLK);

    hipLaunchKernelGGL(wce_main, dim3(MAIN_GX, NBATCH), dim3(MAIN_BLK), 0, stream,
                       pred, target, pS, pC);
    hipLaunchKernelGGL(wce_final, dim3(1), dim3(1024), 0, stream, pS, pC, (float*)d_out);
}